// Round 5
// baseline (1596.137 us; speedup 1.0000x reference)
//
#include <hip/hip_runtime.h>
#include <cstdint>

#define DI __device__ __forceinline__
#define MEMPIN asm volatile("" ::: "memory")

typedef __attribute__((ext_vector_type(8))) short bx8;   // 8 x bf16 (bit pattern)
typedef __attribute__((ext_vector_type(4))) float f4;
typedef unsigned short u16;
typedef unsigned int u32;
typedef __attribute__((ext_vector_type(4))) u32 u32x4;

// ---------------- problem constants ----------------
constexpr int NB = 1024;         // batch
constexpr int NN = 196;          // tokens
constexpr int NC = 384;          // channels
constexpr int NH = 12;           // heads
constexpr int HD = 32;           // head dim
constexpr int C3 = 3 * NC;       // 1152
constexpr int PH = NN * HD;      // 6272 elements per (b,h)

// ======== workspace layout (bytes) ========
constexpr size_t SZ_T    = (size_t)NB * NH * PH * 4;   // 308,281,344 (fp32 tensor)
constexpr size_t SZ_TH   = SZ_T / 2;                   // 154,140,672 (u16 tensor)
constexpr size_t OFF_Q   = 0;                          // q fp32
constexpr size_t OFF_K   = SZ_T;                       // k fp32 ; yh u16 overlays
constexpr size_t OFF_V   = 2 * SZ_T;                   // v bf16 ; yl u16 overlays
constexpr size_t OFF_WQH = OFF_V + SZ_TH;
constexpr size_t SZ_WQ   = (size_t)C3 * NC * 2;        // 884,736
constexpr size_t OFF_WQL = OFF_WQH + SZ_WQ;
constexpr size_t OFF_WPH = OFF_WQL + SZ_WQ;
constexpr size_t SZ_WP   = (size_t)NC * NC * 2;        // 294,912
constexpr size_t OFF_WPL = OFF_WPH + SZ_WP;
constexpr size_t OFF_XH  = OFF_WPL + SZ_WP;
constexpr size_t OFF_XL  = OFF_XH + SZ_TH;

DI void gload_lds16(const void* g, void* l) {
  using GP = const void __attribute__((address_space(1)))*;
  using LP = void __attribute__((address_space(3)))*;
  __builtin_amdgcn_global_load_lds((GP)g, (LP)l, 16, 0, 0);
}

DI u32 cvt_pk_bf16(float lo, float hi) {   // dst = bf16(lo) | bf16(hi)<<16, RNE
  u32 r;
  asm volatile("v_cvt_pk_bf16_f32 %0, %1, %2" : "=v"(r) : "v"(lo), "v"(hi));
  return r;
}
DI float bflo(u32 p) { return __uint_as_float(p << 16); }
DI float bfhi(u32 p) { return __uint_as_float(p & 0xffff0000u); }

// ---------------- kernel: pre-split weight matrices ----------------
__global__ void split_weights(const float* __restrict__ qw, const float* __restrict__ pw,
                              u16* __restrict__ qh, u16* __restrict__ ql,
                              u16* __restrict__ ph, u16* __restrict__ pl)
{
  int i = blockIdx.x * 256 + threadIdx.x;
  if (i < C3 * NC) {
    float f = qw[i];
    u32 u = __float_as_uint(f);
    qh[i] = (u16)(u >> 16);
    float lo = f - __uint_as_float(u & 0xffff0000u);
    u32 ul = __float_as_uint(lo);
    ul += 0x7fffu + ((ul >> 16) & 1u);               // RNE on residual
    ql[i] = (u16)(ul >> 16);
  }
  if (i < NC * NC) {
    float f = pw[i];
    u32 u = __float_as_uint(f);
    ph[i] = (u16)(u >> 16);
    float lo = f - __uint_as_float(u & 0xffff0000u);
    u32 ul = __float_as_uint(lo);
    ul += 0x7fffu + ((ul >> 16) & 1u);
    pl[i] = (u16)(ul >> 16);
  }
}

// ---------------- kernel: pre-split x into bf16 hi/lo ----------------
__global__ void split_x(const float* __restrict__ x, u16* __restrict__ xh, u16* __restrict__ xl)
{
  size_t i = ((size_t)blockIdx.x * 256 + threadIdx.x) * 8;
  f4 a = *(const f4*)(x + i);
  f4 b = *(const f4*)(x + i + 4);
  float v[8] = {a[0], a[1], a[2], a[3], b[0], b[1], b[2], b[3]};
  u32x4 hp, lp;
#pragma unroll
  for (int j = 0; j < 4; ++j) {
    float v0 = v[2 * j], v1 = v[2 * j + 1];
    u32 u0 = __float_as_uint(v0), u1 = __float_as_uint(v1);
    hp[j] = (u0 >> 16) | (u1 & 0xffff0000u);
    float l0 = v0 - __uint_as_float(u0 & 0xffff0000u);
    float l1 = v1 - __uint_as_float(u1 & 0xffff0000u);
    lp[j] = cvt_pk_bf16(l0, l1);
  }
  *(u32x4*)(xh + i) = hp;
  *(u32x4*)(xl + i) = lp;
}

// ================= 8-phase GEMMs =================
// Tile BM=256 x BN=128, BK=32, 8 waves (4M x 2N of 64x64), LDS 2 x (A 32K | B 16K).
// Layout per region: [rows][128B]; column-granule c (16B; c<4 = hi, c>=4 = lo of the
// same k32) stored at slot s = c ^ (row&7)  -> conflict-free b128 reads (verified r4:
// SQ_LDS_BANK_CONFLICT = 0). Linear LDS dest for global_load_lds; inverse XOR applied
// on the per-lane GLOBAL source (rule 21).
// Schedule (T3+T4+T5): 4 phases/K-tile; per phase {ds_read frag ; issue 2 stage loads
// -> s_barrier -> setprio(1) 12 MFMA setprio(0) -> s_barrier}. vmcnt(2) ONCE per
// K-tile at P0 (2 = loads just issued for tile t+1; the older 6 must have landed).
// MEMPIN (empty asm, memory clobber) confines every LDS/global memory op to its phase.

// ---------------- qkv = x @ qkv_w^T + b ; relu/pos ; head-split ----------------
__global__ __launch_bounds__(512, 2) void qkv_gemm8(
    const u16* __restrict__ xh, const u16* __restrict__ xl,
    const u16* __restrict__ wh, const u16* __restrict__ wl,
    const float* __restrict__ bias, const float* __restrict__ pos,
    float* __restrict__ qo, float* __restrict__ ko, u16* __restrict__ vo)
{
  __shared__ __align__(16) char lds[2][49152];
  const int tid  = threadIdx.x;
  const int lane = tid & 63, wv = tid >> 6;
  const int L  = ((int)blockIdx.x & 7) * 882 + ((int)blockIdx.x >> 3);  // 7056 = 8*882
  const int rt = L / 9, ct = L - rt * 9;
  const int m0 = rt * 256, t0 = ct * 128;

  // staging sources: granule g = j*512+tid; row = g>>3; slot = g&7; col-gran c = slot^(row&7)
  const int arow = tid >> 3, slot = tid & 7;
  const u16* spA[4];
  const u16* spB[2];
#pragma unroll
  for (int j = 0; j < 4; ++j) {
    int row = j * 64 + arow;
    int c = slot ^ (row & 7);
    spA[j] = ((c < 4) ? xh : xl) + (size_t)(m0 + row) * NC + (c & 3) * 8;
  }
#pragma unroll
  for (int j = 0; j < 2; ++j) {
    int row = j * 64 + arow;
    int c = slot ^ (row & 7);
    spB[j] = ((c < 4) ? wh : wl) + (size_t)(t0 + row) * NC + (c & 3) * 8;
  }

  auto stageA = [&](char* buf, int j) {
    gload_lds16(spA[j], buf + (j * 512 + tid) * 16);
    spA[j] += 32;
  };
  auto stageB = [&](char* buf, int j) {
    gload_lds16(spB[j], buf + 32768 + (j * 512 + tid) * 16);
    spB[j] += 32;
  };

  const int wm = (wv >> 1) * 64, wn = (wv & 1) * 64;
  const int l15 = lane & 15, l4 = lane >> 4;
  const int sl = l4 ^ (l15 & 7);
  int aoff[4], boff[4];
#pragma unroll
  for (int i = 0; i < 4; ++i) {
    aoff[i] = (wm + i * 16 + l15) * 128 + sl * 16;
    boff[i] = 32768 + (wn + i * 16 + l15) * 128 + sl * 16;
  }

  f4 acc[4][4];
  const f4 fz = {0.f, 0.f, 0.f, 0.f};
#pragma unroll
  for (int i = 0; i < 4; ++i)
#pragma unroll
    for (int j = 0; j < 4; ++j) acc[i][j] = fz;

  // prologue: stage tile 0 (6 loads/thread), no wait
  {
    char* b0 = lds[0];
#pragma unroll
    for (int j = 0; j < 4; ++j) stageA(b0, j);
#pragma unroll
    for (int j = 0; j < 2; ++j) stageB(b0, j);
  }

  for (int t = 0; t < 12; ++t) {
    char* cur = lds[t & 1];
    char* nxt = lds[(t + 1) & 1];
    const bool pf = (t < 11);
    // ---- phase 0: stage A0,A1(next) ; vmcnt ; barrier ; read B(all)+A0 ; MFMA mi=0 ----
    if (pf) {
      stageA(nxt, 0); stageA(nxt, 1);
      asm volatile("s_waitcnt vmcnt(2)" ::: "memory");
    } else {
      asm volatile("s_waitcnt vmcnt(0)" ::: "memory");
    }
    __builtin_amdgcn_s_barrier();
    MEMPIN;
    bx8 bh[4], bl[4];
#pragma unroll
    for (int i = 0; i < 4; ++i) {
      bh[i] = *(const bx8*)(cur + boff[i]);
      bl[i] = *(const bx8*)(cur + (boff[i] ^ 64));
    }
    {
      bx8 ah = *(const bx8*)(cur + aoff[0]);
      bx8 al = *(const bx8*)(cur + (aoff[0] ^ 64));
      MEMPIN;
      __builtin_amdgcn_s_setprio(1);
#pragma unroll
      for (int ni = 0; ni < 4; ++ni) {
        acc[0][ni] = __builtin_amdgcn_mfma_f32_16x16x32_bf16(ah, bh[ni], acc[0][ni], 0, 0, 0);
        acc[0][ni] = __builtin_amdgcn_mfma_f32_16x16x32_bf16(ah, bl[ni], acc[0][ni], 0, 0, 0);
        acc[0][ni] = __builtin_amdgcn_mfma_f32_16x16x32_bf16(al, bh[ni], acc[0][ni], 0, 0, 0);
      }
      __builtin_amdgcn_s_setprio(0);
    }
    __builtin_amdgcn_s_barrier();
    MEMPIN;
    // ---- phases 1..3 ----
#pragma unroll
    for (int mi = 1; mi < 4; ++mi) {
      bx8 ah = *(const bx8*)(cur + aoff[mi]);
      bx8 al = *(const bx8*)(cur + (aoff[mi] ^ 64));
      if (pf) {
        if (mi == 1) { stageA(nxt, 2); stageA(nxt, 3); }
        else if (mi == 2) { stageB(nxt, 0); stageB(nxt, 1); }
      }
      MEMPIN;
      __builtin_amdgcn_s_barrier();
      __builtin_amdgcn_s_setprio(1);
#pragma unroll
      for (int ni = 0; ni < 4; ++ni) {
        acc[mi][ni] = __builtin_amdgcn_mfma_f32_16x16x32_bf16(ah, bh[ni], acc[mi][ni], 0, 0, 0);
        acc[mi][ni] = __builtin_amdgcn_mfma_f32_16x16x32_bf16(ah, bl[ni], acc[mi][ni], 0, 0, 0);
        acc[mi][ni] = __builtin_amdgcn_mfma_f32_16x16x32_bf16(al, bh[ni], acc[mi][ni], 0, 0, 0);
      }
      __builtin_amdgcn_s_setprio(0);
      MEMPIN;
      __builtin_amdgcn_s_barrier();
      MEMPIN;
    }
  }

  // epilogue: bias, relu (q), pos+relu (k), bf16-RNE (v); head-split scatter
  const int s = ct / 3, cb = (ct - s * 3) * 128;   // s: 0=q 1=k 2=v
  float biasv[4];
#pragma unroll
  for (int ni = 0; ni < 4; ++ni) biasv[ni] = bias[t0 + wn + ni * 16 + l15];
#pragma unroll
  for (int mi = 0; mi < 4; ++mi) {
#pragma unroll
    for (int rr = 0; rr < 4; ++rr) {
      int m = m0 + wm + mi * 16 + l4 * 4 + rr;
      int b = m / 196, n = m - b * 196;
      size_t rowb = (size_t)b * 75264 + (size_t)n * 32;
#pragma unroll
      for (int ni = 0; ni < 4; ++ni) {
        int c = cb + wn + ni * 16 + l15;
        float val = acc[mi][ni][rr] + biasv[ni];
        size_t idx = rowb + (size_t)(c >> 5) * 6272 + (c & 31);
        if (s == 0) { qo[idx] = fmaxf(val, 0.f); }
        else if (s == 1) { ko[idx] = fmaxf(val + pos[n * 384 + c], 0.f); }
        else { vo[idx] = (u16)cvt_pk_bf16(val, val); }   // RNE bf16
      }
    }
  }
}

// ---------------- out = y @ proj_w^T + proj_b ----------------
__global__ __launch_bounds__(512, 2) void proj_gemm8(
    const u16* __restrict__ yh, const u16* __restrict__ yl,
    const u16* __restrict__ wh, const u16* __restrict__ wl,
    const float* __restrict__ bias, float* __restrict__ out)
{
  __shared__ __align__(16) char lds[2][49152];
  const int tid  = threadIdx.x;
  const int lane = tid & 63, wv = tid >> 6;
  const int L  = ((int)blockIdx.x & 7) * 294 + ((int)blockIdx.x >> 3);  // 2352 = 8*294
  const int rt = L / 3, ct = L - rt * 3;
  const int m0 = rt * 256, t0 = ct * 128;

  const int arow = tid >> 3, slot = tid & 7;
  const u16* spA[4];
  const u16* spB[2];
#pragma unroll
  for (int j = 0; j < 4; ++j) {
    int row = j * 64 + arow;
    int m = m0 + row;
    int b = m / 196, n = m - b * 196;
    int c = slot ^ (row & 7);
    spA[j] = ((c < 4) ? yh : yl) + (size_t)b * 75264 + n * 32 + (c & 3) * 8;
  }
#pragma unroll
  for (int j = 0; j < 2; ++j) {
    int row = j * 64 + arow;
    int c = slot ^ (row & 7);
    spB[j] = ((c < 4) ? wh : wl) + (size_t)(t0 + row) * NC + (c & 3) * 8;
  }

  auto stageA = [&](char* buf, int j) {          // K-step = one head: stride 6272
    gload_lds16(spA[j], buf + (j * 512 + tid) * 16);
    spA[j] += 6272;
  };
  auto stageB = [&](char* buf, int j) {
    gload_lds16(spB[j], buf + 32768 + (j * 512 + tid) * 16);
    spB[j] += 32;
  };

  const int wm = (wv >> 1) * 64, wn = (wv & 1) * 64;
  const int l15 = lane & 15, l4 = lane >> 4;
  const int sl = l4 ^ (l15 & 7);
  int aoff[4], boff[4];
#pragma unroll
  for (int i = 0; i < 4; ++i) {
    aoff[i] = (wm + i * 16 + l15) * 128 + sl * 16;
    boff[i] = 32768 + (wn + i * 16 + l15) * 128 + sl * 16;
  }

  f4 acc[4][4];
  const f4 fz = {0.f, 0.f, 0.f, 0.f};
#pragma unroll
  for (int i = 0; i < 4; ++i)
#pragma unroll
    for (int j = 0; j < 4; ++j) acc[i][j] = fz;

  {
    char* b0 = lds[0];
#pragma unroll
    for (int j = 0; j < 4; ++j) stageA(b0, j);
#pragma unroll
    for (int j = 0; j < 2; ++j) stageB(b0, j);
  }

  for (int t = 0; t < 12; ++t) {
    char* cur = lds[t & 1];
    char* nxt = lds[(t + 1) & 1];
    const bool pf = (t < 11);
    if (pf) {
      stageA(nxt, 0); stageA(nxt, 1);
      asm volatile("s_waitcnt vmcnt(2)" ::: "memory");
    } else {
      asm volatile("s_waitcnt vmcnt(0)" ::: "memory");
    }
    __builtin_amdgcn_s_barrier();
    MEMPIN;
    bx8 bh[4], bl[4];
#pragma unroll
    for (int i = 0; i < 4; ++i) {
      bh[i] = *(const bx8*)(cur + boff[i]);
      bl[i] = *(const bx8*)(cur + (boff[i] ^ 64));
    }
    {
      bx8 ah = *(const bx8*)(cur + aoff[0]);
      bx8 al = *(const bx8*)(cur + (aoff[0] ^ 64));
      MEMPIN;
      __builtin_amdgcn_s_setprio(1);
#pragma unroll
      for (int ni = 0; ni < 4; ++ni) {
        acc[0][ni] = __builtin_amdgcn_mfma_f32_16x16x32_bf16(ah, bh[ni], acc[0][ni], 0, 0, 0);
        acc[0][ni] = __builtin_amdgcn_mfma_f32_16x16x32_bf16(ah, bl[ni], acc[0][ni], 0, 0, 0);
        acc[0][ni] = __builtin_amdgcn_mfma_f32_16x16x32_bf16(al, bh[ni], acc[0][ni], 0, 0, 0);
      }
      __builtin_amdgcn_s_setprio(0);
    }
    __builtin_amdgcn_s_barrier();
    MEMPIN;
#pragma unroll
    for (int mi = 1; mi < 4; ++mi) {
      bx8 ah = *(const bx8*)(cur + aoff[mi]);
      bx8 al = *(const bx8*)(cur + (aoff[mi] ^ 64));
      if (pf) {
        if (mi == 1) { stageA(nxt, 2); stageA(nxt, 3); }
        else if (mi == 2) { stageB(nxt, 0); stageB(nxt, 1); }
      }
      MEMPIN;
      __builtin_amdgcn_s_barrier();
      __builtin_amdgcn_s_setprio(1);
#pragma unroll
      for (int ni = 0; ni < 4; ++ni) {
        acc[mi][ni] = __builtin_amdgcn_mfma_f32_16x16x32_bf16(ah, bh[ni], acc[mi][ni], 0, 0, 0);
        acc[mi][ni] = __builtin_amdgcn_mfma_f32_16x16x32_bf16(ah, bl[ni], acc[mi][ni], 0, 0, 0);
        acc[mi][ni] = __builtin_amdgcn_mfma_f32_16x16x32_bf16(al, bh[ni], acc[mi][ni], 0, 0, 0);
      }
      __builtin_amdgcn_s_setprio(0);
      MEMPIN;
      __builtin_amdgcn_s_barrier();
      MEMPIN;
    }
  }

  float biasv[4];
#pragma unroll
  for (int ni = 0; ni < 4; ++ni) biasv[ni] = bias[t0 + wn + ni * 16 + l15];
#pragma unroll
  for (int mi = 0; mi < 4; ++mi) {
#pragma unroll
    for (int rr = 0; rr < 4; ++rr) {
      int m = m0 + wm + mi * 16 + l4 * 4 + rr;
      size_t ob = (size_t)m * 384 + t0 + wn;
#pragma unroll
      for (int ni = 0; ni < 4; ++ni)
        out[ob + ni * 16 + l15] = acc[mi][ni][rr] + biasv[ni];
    }
  }
}

// ---------------- per-(b,h) linear attention + depthwise conv ----------------
__global__ __launch_bounds__(256, 4) void attn_conv(
    const float* __restrict__ q, const float* k,
    const u16* v16, u16* yh, u16* yl,
    const float* __restrict__ dwc_w, const float* __restrict__ dwc_b)
{
  __shared__ __align__(16) u16  sv[NN * 40];    // bf16 v, rows padded to 40 (80B)
  __shared__ __align__(16) u16  sfm[NN * 40];   // bf16 conv output
  __shared__ __align__(16) float skv[32 * 36];  // kv fp32, row pad 36
  __shared__ float sksum[32];

  const int tid = threadIdx.x;
  const size_t base = (size_t)blockIdx.x * PH;
  const u16*   vp = v16 + base;
  const float* kp = k + base;
  const float* qp = q + base;
  u16* yhp = yh + base;
  u16* ylp = yl + base;
  char* svb  = (char*)sv;
  char* sfmb = (char*)sfm;

  // ---- phase 1: stage v bf16 -> padded LDS ----
  for (int c = tid; c < 784; c += 256) {
    u32x4 pk = *(const u32x4*)(vp + c * 8);
    *(u32x4*)(svb + (c >> 2) * 80 + (c & 3) * 16) = pk;
  }
  __syncthreads();

  // ---- phase 2: kv[c][d] = sum_n k[n][c]*v[n][d]  (8-way n-split + butterfly) ----
  {
    const int c = tid >> 3, ns = tid & 7;
    float acc[33];
#pragma unroll
    for (int d = 0; d < 33; ++d) acc[d] = 0.f;
    for (int i = 0; i < 25; ++i) {
      int n = i * 8 + ns;
      if (n < 196) {
        float kc = kp[n * 32 + c];
#pragma unroll
        for (int g = 0; g < 4; ++g) {
          u32x4 r = *(const u32x4*)(svb + n * 80 + g * 16);
#pragma unroll
          for (int j = 0; j < 4; ++j) {
            acc[g * 8 + 2 * j]     += kc * bflo(r[j]);
            acc[g * 8 + 2 * j + 1] += kc * bfhi(r[j]);
          }
        }
        acc[32] += kc;
      }
    }
#pragma unroll
    for (int off = 1; off <= 4; off <<= 1) {
#pragma unroll
      for (int d = 0; d < 33; ++d) acc[d] += __shfl_xor(acc[d], off);
    }
    if (ns == 0) {
#pragma unroll
      for (int d4 = 0; d4 < 32; d4 += 4) {
        f4 w; w[0] = acc[d4]; w[1] = acc[d4+1]; w[2] = acc[d4+2]; w[3] = acc[d4+3];
        *(f4*)&skv[c * 36 + d4] = w;
      }
      sksum[c] = acc[32];
    }
  }

  // ---- phase 3: depthwise 5x5 conv on v (d-pair threads), fm -> bf16 LDS ----
  {
    const int dp = tid & 15, py = tid >> 4;
    if (py < 14) {
      const int d0 = 2 * dp;
      float fm0[14], fm1[14];
      const float b0 = dwc_b[d0], b1 = dwc_b[d0 + 1];
#pragma unroll
      for (int px = 0; px < 14; ++px) { fm0[px] = b0; fm1[px] = b1; }
#pragma unroll
      for (int ky = 0; ky < 5; ++ky) {
        int yy = py + ky - 2;
        if (yy < 0 || yy >= 14) continue;
        float w0[5], w1[5];
#pragma unroll
        for (int t = 0; t < 5; ++t) {
          w0[t] = dwc_w[d0 * 25 + ky * 5 + t];
          w1[t] = dwc_w[(d0 + 1) * 25 + ky * 5 + t];
        }
        float r0[14], r1[14];
#pragma unroll
        for (int xx = 0; xx < 14; ++xx) {
          u32 pr = *(const u32*)(svb + (yy * 14 + xx) * 80 + dp * 4);
          r0[xx] = bflo(pr); r1[xx] = bfhi(pr);
        }
#pragma unroll
        for (int px = 0; px < 14; ++px) {
#pragma unroll
          for (int kx = 0; kx < 5; ++kx) {
            int xx = px + kx - 2;
            if (xx < 0 || xx > 13) continue;
            fm0[px] += w0[kx] * r0[xx];
            fm1[px] += w1[kx] * r1[xx];
          }
        }
      }
#pragma unroll
      for (int px = 0; px < 14; ++px)
        *(u32*)(sfmb + (py * 14 + px) * 80 + dp * 4) = cvt_pk_bf16(fm0[px], fm1[px]);
    }
  }
  __syncthreads();

  // ---- phase 4: y = z*(q@kv) + fm ; write split yh/yl ----
  {
    const int dp = tid & 15, ng = tid >> 4;
    const int d0 = 2 * dp;
    float kv0[32], kv1[32], ks[32];
#pragma unroll
    for (int c = 0; c < 32; ++c) {
      const float* p = &skv[c * 36 + d0];
      kv0[c] = p[0]; kv1[c] = p[1];
    }
#pragma unroll
    for (int c = 0; c < 32; ++c) ks[c] = sksum[c];
#pragma unroll 2
    for (int i = 0; i < 13; ++i) {
      int n = i * 16 + ng;
      if (n < 196) {
        float o0 = 0.f, o1 = 0.f, pz = 0.f;
#pragma unroll
        for (int c4 = 0; c4 < 32; c4 += 4) {
          f4 qv = *(const f4*)(qp + n * 32 + c4);
#pragma unroll
          for (int j = 0; j < 4; ++j) {
            o0 += qv[j] * kv0[c4 + j];
            o1 += qv[j] * kv1[c4 + j];
            pz += qv[j] * ks[c4 + j];
          }
        }
        float z = 1.f / (pz + 1e-6f);
        u32 fmp = *(const u32*)(sfmb + n * 80 + dp * 4);
        float r0 = fmaf(o0, z, bflo(fmp));
        float r1 = fmaf(o1, z, bfhi(fmp));
        u32 u0 = __float_as_uint(r0), u1 = __float_as_uint(r1);
        u32 hpk = (u0 >> 16) | (u1 & 0xffff0000u);
        float l0 = r0 - __uint_as_float(u0 & 0xffff0000u);
        float l1 = r1 - __uint_as_float(u1 & 0xffff0000u);
        u32 lpk = cvt_pk_bf16(l0, l1);
        *(u32*)(yhp + n * 32 + d0) = hpk;
        *(u32*)(ylp + n * 32 + d0) = lpk;
      }
    }
  }
}

// ---------------- launcher ----------------
extern "C" void kernel_launch(void* const* d_in, const int* in_sizes, int n_in,
                              void* d_out, int out_size, void* d_ws, size_t ws_size,
                              hipStream_t stream)
{
  const float* x      = (const float*)d_in[0];
  const float* qkv_w  = (const float*)d_in[1];
  const float* qkv_b  = (const float*)d_in[2];
  const float* proj_w = (const float*)d_in[3];
  const float* proj_b = (const float*)d_in[4];
  const float* dwc_w  = (const float*)d_in[5];
  const float* dwc_b  = (const float*)d_in[6];
  const float* pos    = (const float*)d_in[7];
  float* out = (float*)d_out;
  char* ws = (char*)d_ws;

  float* qb  = (float*)(ws + OFF_Q);
  float* kb  = (float*)(ws + OFF_K);
  u16*   vb  = (u16*)(ws + OFF_V);
  u16*   wqh = (u16*)(ws + OFF_WQH);
  u16*   wql = (u16*)(ws + OFF_WQL);
  u16*   wph = (u16*)(ws + OFF_WPH);
  u16*   wpl = (u16*)(ws + OFF_WPL);
  u16*   xh  = (u16*)(ws + OFF_XH);
  u16*   xl  = (u16*)(ws + OFF_XL);
  u16*   yh  = (u16*)(ws + OFF_K);   // overlays k (consumed in attn before write)
  u16*   yl  = (u16*)(ws + OFF_V);   // overlays v (consumed in attn before write)

  split_weights<<<1728, 256, 0, stream>>>(qkv_w, proj_w, wqh, wql, wph, wpl);
  split_x<<<37632, 256, 0, stream>>>(x, xh, xl);
  qkv_gemm8<<<7056, 512, 0, stream>>>(xh, xl, wqh, wql, qkv_b, pos, qb, kb, vb);
  attn_conv<<<12288, 256, 0, stream>>>(qb, kb, vb, yh, yl, dwc_w, dwc_b);
  proj_gemm8<<<2352, 512, 0, stream>>>(yh, yl, wph, wpl, proj_b, out);
}

// Round 6
// 1372.801 us; speedup vs baseline: 1.1627x; 1.1627x over previous
//
#include <hip/hip_runtime.h>
#include <hip/hip_fp16.h>
#include <cstdint>

#define DI __device__ __forceinline__

typedef __attribute__((ext_vector_type(8))) short bx8;        // 8 x bf16 bits
typedef __attribute__((ext_vector_type(8))) _Float16 hx8;     // 8 x fp16
typedef __attribute__((ext_vector_type(4))) float f4;
typedef unsigned short u16;
typedef unsigned int u32;
typedef __attribute__((ext_vector_type(4))) u32 u32x4;

// ---------------- problem constants ----------------
constexpr int NB = 1024;
constexpr int NN = 196;
constexpr int NC = 384;
constexpr int NH = 12;
constexpr int HD = 32;
constexpr int C3 = 3 * NC;       // 1152
constexpr int PH = NN * HD;      // 6272 per (b,h)

// ======== workspace layout (bytes) ========
constexpr size_t SZ_TH   = (size_t)NB * NH * PH * 2;   // 154,140,672 (u16 tensor)
constexpr size_t OFF_Q   = 0;                          // q fp16
constexpr size_t OFF_K   = SZ_TH;                      // k fp16 ; yh (bf16 hi) overlays
constexpr size_t OFF_V   = 2 * SZ_TH;                  // v bf16 ; yl (bf16 lo) overlays
constexpr size_t OFF_WQF = 3 * SZ_TH;                  // qkv_w fp16
constexpr size_t SZ_WQ   = (size_t)C3 * NC * 2;        // 884,736
constexpr size_t OFF_WPH = OFF_WQF + SZ_WQ;            // proj_w bf16 hi
constexpr size_t SZ_WP   = (size_t)NC * NC * 2;        // 294,912
constexpr size_t OFF_WPL = OFF_WPH + SZ_WP;            // proj_w bf16 lo
constexpr size_t OFF_XF  = OFF_WPL + SZ_WP;            // x fp16

DI void gload_lds16(const void* g, void* l) {
  using GP = const void __attribute__((address_space(1)))*;
  using LP = void __attribute__((address_space(3)))*;
  __builtin_amdgcn_global_load_lds((GP)g, (LP)l, 16, 0, 0);
}

DI u32 cvt_pk_bf16(float lo, float hi) {   // dst = bf16(lo) | bf16(hi)<<16, RNE
  u32 r;
  asm volatile("v_cvt_pk_bf16_f32 %0, %1, %2" : "=v"(r) : "v"(lo), "v"(hi));
  return r;
}
DI float bflo(u32 p) { return __uint_as_float(p << 16); }
DI float bfhi(u32 p) { return __uint_as_float(p & 0xffff0000u); }
DI float h2f(u16 v)  { _Float16 h = __builtin_bit_cast(_Float16, v); return (float)h; }
DI u16   f2h(float f){ _Float16 h = (_Float16)f; return __builtin_bit_cast(u16, h); }

// ---------------- kernel: convert weights (qkv->fp16, proj->bf16 hi/lo) ----------------
__global__ void split_weights(const float* __restrict__ qw, const float* __restrict__ pw,
                              u16* __restrict__ qf, u16* __restrict__ ph, u16* __restrict__ pl)
{
  int i = blockIdx.x * 256 + threadIdx.x;
  if (i < C3 * NC) {
    qf[i] = f2h(qw[i]);                               // RNE fp16
  }
  if (i < NC * NC) {
    float f = pw[i];
    u32 u = __float_as_uint(f);
    ph[i] = (u16)(u >> 16);                           // truncate hi
    float lo = f - __uint_as_float(u & 0xffff0000u);
    u32 ul = __float_as_uint(lo);
    ul += 0x7fffu + ((ul >> 16) & 1u);                // RNE residual
    pl[i] = (u16)(ul >> 16);
  }
}

// ---------------- kernel: x -> fp16 ----------------
__global__ void cvt_x_f16(const float* __restrict__ x, u16* __restrict__ xf)
{
  size_t i = ((size_t)blockIdx.x * 256 + threadIdx.x) * 8;
  f4 a = *(const f4*)(x + i);
  f4 b = *(const f4*)(x + i + 4);
  u16 o[8];
  o[0]=f2h(a[0]); o[1]=f2h(a[1]); o[2]=f2h(a[2]); o[3]=f2h(a[3]);
  o[4]=f2h(b[0]); o[5]=f2h(b[1]); o[6]=f2h(b[2]); o[7]=f2h(b[3]);
  u32x4 pk;
#pragma unroll
  for (int j = 0; j < 4; ++j) pk[j] = (u32)o[2*j] | ((u32)o[2*j+1] << 16);
  *(u32x4*)(xf + i) = pk;
}

// ---------------- qkv = x @ qkv_w^T + b (pure fp16 MFMA) ; relu/pos ; head-split ----------------
// 128x128 tile, BK=32, 4 waves, 2x16KB LDS -> 4 blocks/CU. LDS rows 64B (32 fp16),
// granule c (16B, 0..3) stored at slot c^(row&3): uniform 8 dwords/bank per b128 read.
// 2-phase schedule (round-4 proven): syncthreads; stage(next); ds_read; 16 MFMA.
__global__ __launch_bounds__(256, 4) void qkv_gemm_f16(
    const u16* __restrict__ xf, const u16* __restrict__ wf,
    const float* __restrict__ bias, const float* __restrict__ pos,
    u16* __restrict__ qo, u16* __restrict__ ko, u16* __restrict__ vo)
{
  __shared__ __align__(16) char lds[2][16384];   // A 8K | B 8K
  const int tid  = threadIdx.x;
  const int lane = tid & 63, wv = tid >> 6;
  const int L  = ((int)blockIdx.x & 7) * 1764 + ((int)blockIdx.x >> 3); // 14112 = 8*1764
  const int rt = L / 9, ct = L - rt * 9;
  const int m0 = rt * 128, t0 = ct * 128;

  // staging: granule g = j*256+tid; row = g>>2; slot = g&3; col-granule c = slot^(row&3)
  const u16* spA[2];
  const u16* spB[2];
#pragma unroll
  for (int j = 0; j < 2; ++j) {
    int g = j * 256 + tid;
    int row = g >> 2, slot = g & 3;
    int c = slot ^ (row & 3);
    spA[j] = xf + (size_t)(m0 + row) * NC + c * 8;
    spB[j] = wf + (size_t)(t0 + row) * NC + c * 8;
  }

  auto stage = [&](char* buf) {
#pragma unroll
    for (int j = 0; j < 2; ++j) {
      gload_lds16(spA[j], buf + (j * 256 + tid) * 16);
      spA[j] += 32;
      gload_lds16(spB[j], buf + 8192 + (j * 256 + tid) * 16);
      spB[j] += 32;
    }
  };

  const int wm = (wv & 1) * 64, wn = (wv >> 1) * 64;
  const int l15 = lane & 15, l4 = lane >> 4;
  const int sl = l4 ^ (l15 & 3);
  int aoff[4], boff[4];
#pragma unroll
  for (int i = 0; i < 4; ++i) {
    aoff[i] = (wm + i * 16 + l15) * 64 + sl * 16;
    boff[i] = 8192 + (wn + i * 16 + l15) * 64 + sl * 16;
  }

  f4 acc[4][4];
  const f4 fz = {0.f, 0.f, 0.f, 0.f};
#pragma unroll
  for (int i = 0; i < 4; ++i)
#pragma unroll
    for (int j = 0; j < 4; ++j) acc[i][j] = fz;

  stage(lds[0]);
  for (int kt = 0; kt < 12; ++kt) {
    __syncthreads();
    if (kt < 11) stage(lds[(kt + 1) & 1]);
    char* buf = lds[kt & 1];
    hx8 af[4], bf4[4];
#pragma unroll
    for (int i = 0; i < 4; ++i) {
      af[i]  = *(const hx8*)(buf + aoff[i]);
      bf4[i] = *(const hx8*)(buf + boff[i]);
    }
#pragma unroll
    for (int mi = 0; mi < 4; ++mi)
#pragma unroll
      for (int ni = 0; ni < 4; ++ni)
        acc[mi][ni] = __builtin_amdgcn_mfma_f32_16x16x32_f16(af[mi], bf4[ni], acc[mi][ni], 0, 0, 0);
  }

  // epilogue: bias; q: relu->fp16 ; k: +pos,relu->fp16 ; v: ->bf16 ; head-split scatter
  const int s = ct / 3, cb = (ct - s * 3) * 128;   // s: 0=q 1=k 2=v
  float biasv[4];
#pragma unroll
  for (int ni = 0; ni < 4; ++ni) biasv[ni] = bias[t0 + wn + ni * 16 + l15];
#pragma unroll
  for (int mi = 0; mi < 4; ++mi) {
#pragma unroll
    for (int rr = 0; rr < 4; ++rr) {
      int m = m0 + wm + mi * 16 + l4 * 4 + rr;
      int b = m / 196, n = m - b * 196;
      size_t rowb = (size_t)b * 75264 + (size_t)n * 32;
#pragma unroll
      for (int ni = 0; ni < 4; ++ni) {
        int c = cb + wn + ni * 16 + l15;
        float val = acc[mi][ni][rr] + biasv[ni];
        size_t idx = rowb + (size_t)(c >> 5) * 6272 + (c & 31);
        if (s == 0)      { qo[idx] = f2h(fmaxf(val, 0.f)); }
        else if (s == 1) { ko[idx] = f2h(fmaxf(val + pos[n * 384 + c], 0.f)); }
        else             { vo[idx] = (u16)cvt_pk_bf16(val, val); }
      }
    }
  }
}

// ---------------- per-(b,h) linear attention + depthwise conv (fp16 q/k, bf16 v) ----------------
__global__ __launch_bounds__(256, 4) void attn_conv(
    const u16* __restrict__ q, const u16* k,
    const u16* v16, u16* yh, u16* yl,
    const float* __restrict__ dwc_w, const float* __restrict__ dwc_b)
{
  __shared__ __align__(16) u16  sv[NN * 40];    // bf16 v, rows padded to 40 (80B)
  __shared__ __align__(16) u16  sfm[NN * 40];   // bf16 conv output
  __shared__ __align__(16) float skv[32 * 36];  // kv fp32, row pad 36
  __shared__ float sksum[32];

  const int tid = threadIdx.x;
  const size_t base = (size_t)blockIdx.x * PH;
  const u16* vp = v16 + base;
  const u16* kp = k + base;
  const u16* qp = q + base;
  u16* yhp = yh + base;
  u16* ylp = yl + base;
  char* svb  = (char*)sv;
  char* sfmb = (char*)sfm;

  // ---- phase 1: stage v bf16 -> padded LDS ----
  for (int c = tid; c < 784; c += 256) {
    u32x4 pk = *(const u32x4*)(vp + c * 8);
    *(u32x4*)(svb + (c >> 2) * 80 + (c & 3) * 16) = pk;
  }
  __syncthreads();

  // ---- phase 2: kv[c][d] = sum_n k[n][c]*v[n][d]  (8-way n-split + butterfly) ----
  {
    const int c = tid >> 3, ns = tid & 7;
    float acc[33];
#pragma unroll
    for (int d = 0; d < 33; ++d) acc[d] = 0.f;
    for (int i = 0; i < 25; ++i) {
      int n = i * 8 + ns;
      if (n < 196) {
        float kc = h2f(kp[n * 32 + c]);
#pragma unroll
        for (int g = 0; g < 4; ++g) {
          u32x4 r = *(const u32x4*)(svb + n * 80 + g * 16);
#pragma unroll
          for (int j = 0; j < 4; ++j) {
            acc[g * 8 + 2 * j]     += kc * bflo(r[j]);
            acc[g * 8 + 2 * j + 1] += kc * bfhi(r[j]);
          }
        }
        acc[32] += kc;
      }
    }
#pragma unroll
    for (int off = 1; off <= 4; off <<= 1) {
#pragma unroll
      for (int d = 0; d < 33; ++d) acc[d] += __shfl_xor(acc[d], off);
    }
    if (ns == 0) {
#pragma unroll
      for (int d4 = 0; d4 < 32; d4 += 4) {
        f4 w; w[0] = acc[d4]; w[1] = acc[d4+1]; w[2] = acc[d4+2]; w[3] = acc[d4+3];
        *(f4*)&skv[c * 36 + d4] = w;
      }
      sksum[c] = acc[32];
    }
  }

  // ---- phase 3: depthwise 5x5 conv on v (d-pair threads), fm -> bf16 LDS ----
  {
    const int dp = tid & 15, py = tid >> 4;
    if (py < 14) {
      const int d0 = 2 * dp;
      float fm0[14], fm1[14];
      const float b0 = dwc_b[d0], b1 = dwc_b[d0 + 1];
#pragma unroll
      for (int px = 0; px < 14; ++px) { fm0[px] = b0; fm1[px] = b1; }
#pragma unroll
      for (int ky = 0; ky < 5; ++ky) {
        int yy = py + ky - 2;
        if (yy < 0 || yy >= 14) continue;
        float w0[5], w1[5];
#pragma unroll
        for (int t = 0; t < 5; ++t) {
          w0[t] = dwc_w[d0 * 25 + ky * 5 + t];
          w1[t] = dwc_w[(d0 + 1) * 25 + ky * 5 + t];
        }
        float r0[14], r1[14];
#pragma unroll
        for (int xx = 0; xx < 14; ++xx) {
          u32 pr = *(const u32*)(svb + (yy * 14 + xx) * 80 + dp * 4);
          r0[xx] = bflo(pr); r1[xx] = bfhi(pr);
        }
#pragma unroll
        for (int px = 0; px < 14; ++px) {
#pragma unroll
          for (int kx = 0; kx < 5; ++kx) {
            int xx = px + kx - 2;
            if (xx < 0 || xx > 13) continue;
            fm0[px] += w0[kx] * r0[xx];
            fm1[px] += w1[kx] * r1[xx];
          }
        }
      }
#pragma unroll
      for (int px = 0; px < 14; ++px)
        *(u32*)(sfmb + (py * 14 + px) * 80 + dp * 4) = cvt_pk_bf16(fm0[px], fm1[px]);
    }
  }
  __syncthreads();

  // ---- phase 4: y = z*(q@kv) + fm ; write split yh/yl ----
  {
    const int dp = tid & 15, ng = tid >> 4;
    const int d0 = 2 * dp;
    float kv0[32], kv1[32], ks[32];
#pragma unroll
    for (int c = 0; c < 32; ++c) {
      const float* p = &skv[c * 36 + d0];
      kv0[c] = p[0]; kv1[c] = p[1];
    }
#pragma unroll
    for (int c = 0; c < 32; ++c) ks[c] = sksum[c];
#pragma unroll 2
    for (int i = 0; i < 13; ++i) {
      int n = i * 16 + ng;
      if (n < 196) {
        float qv[32];
#pragma unroll
        for (int g = 0; g < 4; ++g) {
          u32x4 qw = *(const u32x4*)(qp + (size_t)n * 32 + g * 8);
#pragma unroll
          for (int j = 0; j < 4; ++j) {
            qv[g * 8 + 2 * j]     = h2f((u16)(qw[j] & 0xffffu));
            qv[g * 8 + 2 * j + 1] = h2f((u16)(qw[j] >> 16));
          }
        }
        float o0 = 0.f, o1 = 0.f, pz = 0.f;
#pragma unroll
        for (int c = 0; c < 32; ++c) {
          o0 += qv[c] * kv0[c];
          o1 += qv[c] * kv1[c];
          pz += qv[c] * ks[c];
        }
        float z = 1.f / (pz + 1e-6f);
        u32 fmp = *(const u32*)(sfmb + n * 80 + dp * 4);
        float r0 = fmaf(o0, z, bflo(fmp));
        float r1 = fmaf(o1, z, bfhi(fmp));
        u32 u0 = __float_as_uint(r0), u1 = __float_as_uint(r1);
        u32 hpk = (u0 >> 16) | (u1 & 0xffff0000u);
        float l0 = r0 - __uint_as_float(u0 & 0xffff0000u);
        float l1 = r1 - __uint_as_float(u1 & 0xffff0000u);
        u32 lpk = cvt_pk_bf16(l0, l1);
        *(u32*)(yhp + n * 32 + d0) = hpk;
        *(u32*)(ylp + n * 32 + d0) = lpk;
      }
    }
  }
}

// ---------------- out = y @ proj_w^T + proj_b (bf16 3-term split; round-4 proven) ----------------
__global__ __launch_bounds__(256, 2) void proj_gemm(
    const u16* __restrict__ yh, const u16* __restrict__ yl,
    const u16* __restrict__ wh, const u16* __restrict__ wl,
    const float* __restrict__ bias, float* __restrict__ out)
{
  __shared__ __align__(16) char lds[2][32768];
  const int tid  = threadIdx.x;
  const int lane = tid & 63, wv = tid >> 6;
  const int L  = ((int)blockIdx.x & 7) * 588 + ((int)blockIdx.x >> 3);  // 4704 = 8*588
  const int rt = L / 3, ct = L - rt * 3;
  const int m0 = rt * 128, t0 = ct * 128;

  const int srow = tid >> 3;
  const int c8s  = (tid & 7) ^ (srow & 7);
  const int doff = (c8s & 3) * 8;
  const u16* sp[8];
#pragma unroll
  for (int jj = 0; jj < 4; ++jj) {
    int m = m0 + jj * 32 + srow;
    int b = m / 196, n = m - b * 196;
    const u16* basep = (c8s < 4) ? yh : yl;
    sp[jj] = basep + ((size_t)b * 12 * 196 + n) * 32 + doff;   // +kt*6272 per head
  }
#pragma unroll
  for (int jj = 4; jj < 8; ++jj) {
    const u16* basep = (c8s < 4) ? wh : wl;
    sp[jj] = basep + (size_t)(t0 + (jj - 4) * 32 + srow) * NC + doff;
  }

  auto stage = [&](char* buf) {
#pragma unroll
    for (int jj = 0; jj < 8; ++jj) {
      gload_lds16(sp[jj], buf + jj * 4096 + tid * 16);
      sp[jj] += (jj < 4) ? 6272 : 32;
    }
  };

  const int wm = (wv & 1) * 64, wn = (wv >> 1) * 64;
  const int l15 = lane & 15, l4 = lane >> 4;
  const int sl = l4 ^ (l15 & 7);
  int aoff[4], boff[4];
#pragma unroll
  for (int i = 0; i < 4; ++i) {
    aoff[i] = (wm + i * 16 + l15) * 128 + sl * 16;
    boff[i] = (wn + i * 16 + l15) * 128 + sl * 16;
  }

  f4 acc[4][4];
  const f4 fz = {0.f, 0.f, 0.f, 0.f};
#pragma unroll
  for (int i = 0; i < 4; ++i)
#pragma unroll
    for (int j = 0; j < 4; ++j) acc[i][j] = fz;

  stage(lds[0]);
  for (int kt = 0; kt < 12; ++kt) {
    __syncthreads();
    if (kt < 11) stage(lds[(kt + 1) & 1]);
    char* bufA = lds[kt & 1];
    char* bufB = bufA + 16384;
    bx8 ah[4], al[4], bh4[4], bl4[4];
#pragma unroll
    for (int i = 0; i < 4; ++i) {
      ah[i]  = *(const bx8*)(bufA + aoff[i]);
      al[i]  = *(const bx8*)(bufA + (aoff[i] ^ 64));
      bh4[i] = *(const bx8*)(bufB + boff[i]);
      bl4[i] = *(const bx8*)(bufB + (boff[i] ^ 64));
    }
#pragma unroll
    for (int mi = 0; mi < 4; ++mi)
#pragma unroll
      for (int ni = 0; ni < 4; ++ni) {
        acc[mi][ni] = __builtin_amdgcn_mfma_f32_16x16x32_bf16(ah[mi], bh4[ni], acc[mi][ni], 0, 0, 0);
        acc[mi][ni] = __builtin_amdgcn_mfma_f32_16x16x32_bf16(ah[mi], bl4[ni], acc[mi][ni], 0, 0, 0);
        acc[mi][ni] = __builtin_amdgcn_mfma_f32_16x16x32_bf16(al[mi], bh4[ni], acc[mi][ni], 0, 0, 0);
      }
  }

  float biasv[4];
#pragma unroll
  for (int ni = 0; ni < 4; ++ni) biasv[ni] = bias[t0 + wn + ni * 16 + l15];
#pragma unroll
  for (int mi = 0; mi < 4; ++mi) {
#pragma unroll
    for (int rr = 0; rr < 4; ++rr) {
      int m = m0 + wm + mi * 16 + l4 * 4 + rr;
      size_t ob = (size_t)m * 384 + t0 + wn;
#pragma unroll
      for (int ni = 0; ni < 4; ++ni)
        out[ob + ni * 16 + l15] = acc[mi][ni][rr] + biasv[ni];
    }
  }
}

// ---------------- launcher ----------------
extern "C" void kernel_launch(void* const* d_in, const int* in_sizes, int n_in,
                              void* d_out, int out_size, void* d_ws, size_t ws_size,
                              hipStream_t stream)
{
  const float* x      = (const float*)d_in[0];
  const float* qkv_w  = (const float*)d_in[1];
  const float* qkv_b  = (const float*)d_in[2];
  const float* proj_w = (const float*)d_in[3];
  const float* proj_b = (const float*)d_in[4];
  const float* dwc_w  = (const float*)d_in[5];
  const float* dwc_b  = (const float*)d_in[6];
  const float* pos    = (const float*)d_in[7];
  float* out = (float*)d_out;
  char* ws = (char*)d_ws;

  u16* qb  = (u16*)(ws + OFF_Q);     // q fp16
  u16* kb  = (u16*)(ws + OFF_K);     // k fp16
  u16* vb  = (u16*)(ws + OFF_V);     // v bf16
  u16* wqf = (u16*)(ws + OFF_WQF);
  u16* wph = (u16*)(ws + OFF_WPH);
  u16* wpl = (u16*)(ws + OFF_WPL);
  u16* xf  = (u16*)(ws + OFF_XF);
  u16* yh  = (u16*)(ws + OFF_K);     // overlays k (consumed in attn before write)
  u16* yl  = (u16*)(ws + OFF_V);     // overlays v (consumed in attn before write)

  split_weights<<<1728, 256, 0, stream>>>(qkv_w, proj_w, wqf, wph, wpl);
  cvt_x_f16<<<37632, 256, 0, stream>>>(x, xf);
  qkv_gemm_f16<<<14112, 256, 0, stream>>>(xf, wqf, qkv_b, pos, qb, kb, vb);
  attn_conv<<<12288, 256, 0, stream>>>(qb, kb, vb, yh, yl, dwc_w, dwc_b);
  proj_gemm<<<4704, 256, 0, stream>>>(yh, yl, wph, wpl, proj_b, out);
}

// Round 7
// 1063.647 us; speedup vs baseline: 1.5006x; 1.2907x over previous
//
#include <hip/hip_runtime.h>
#include <hip/hip_fp16.h>
#include <cstdint>

#define DI __device__ __forceinline__

typedef __attribute__((ext_vector_type(8))) _Float16 hx8;     // 8 x fp16
typedef __attribute__((ext_vector_type(4))) float f4;
typedef unsigned short u16;
typedef unsigned int u32;
typedef __attribute__((ext_vector_type(4))) u32 u32x4;

// ---------------- problem constants ----------------
constexpr int NB = 1024;
constexpr int NN = 196;
constexpr int NC = 384;
constexpr int NH = 12;
constexpr int HD = 32;
constexpr int C3 = 3 * NC;       // 1152
constexpr int PH = NN * HD;      // 6272 per (b,h)

// ======== workspace layout (bytes) ========
constexpr size_t SZ_TH   = (size_t)NB * NH * PH * 2;   // 154,140,672 (u16 tensor)
constexpr size_t OFF_Q   = 0;                          // q fp16
constexpr size_t OFF_K   = SZ_TH;                      // k fp16 ; y fp16 overlays
constexpr size_t OFF_V   = 2 * SZ_TH;                  // v bf16
constexpr size_t OFF_WQF = 3 * SZ_TH;                  // qkv_w fp16
constexpr size_t SZ_WQ   = (size_t)C3 * NC * 2;        // 884,736
constexpr size_t OFF_WPF = OFF_WQF + SZ_WQ;            // proj_w fp16
constexpr size_t SZ_WP   = (size_t)NC * NC * 2;        // 294,912
constexpr size_t OFF_XF  = OFF_WPF + SZ_WP;            // x fp16

DI void gload_lds16(const void* g, void* l) {
  using GP = const void __attribute__((address_space(1)))*;
  using LP = void __attribute__((address_space(3)))*;
  __builtin_amdgcn_global_load_lds((GP)g, (LP)l, 16, 0, 0);
}

DI u32 cvt_pk_bf16(float lo, float hi) {   // dst = bf16(lo) | bf16(hi)<<16, RNE
  u32 r;
  asm volatile("v_cvt_pk_bf16_f32 %0, %1, %2" : "=v"(r) : "v"(lo), "v"(hi));
  return r;
}
DI float bflo(u32 p) { return __uint_as_float(p << 16); }
DI float bfhi(u32 p) { return __uint_as_float(p & 0xffff0000u); }
DI float h2f(u16 v)  { _Float16 h = __builtin_bit_cast(_Float16, v); return (float)h; }
DI u16   f2h(float f){ _Float16 h = (_Float16)f; return __builtin_bit_cast(u16, h); }

// ---------------- kernel: convert weights to fp16 ----------------
__global__ void split_weights(const float* __restrict__ qw, const float* __restrict__ pw,
                              u16* __restrict__ qf, u16* __restrict__ pf)
{
  int i = blockIdx.x * 256 + threadIdx.x;
  if (i < C3 * NC) qf[i] = f2h(qw[i]);
  if (i < NC * NC) pf[i] = f2h(pw[i]);
}

// ---------------- kernel: x -> fp16 ----------------
__global__ void cvt_x_f16(const float* __restrict__ x, u16* __restrict__ xf)
{
  size_t i = ((size_t)blockIdx.x * 256 + threadIdx.x) * 8;
  f4 a = *(const f4*)(x + i);
  f4 b = *(const f4*)(x + i + 4);
  u16 o[8];
  o[0]=f2h(a[0]); o[1]=f2h(a[1]); o[2]=f2h(a[2]); o[3]=f2h(a[3]);
  o[4]=f2h(b[0]); o[5]=f2h(b[1]); o[6]=f2h(b[2]); o[7]=f2h(b[3]);
  u32x4 pk;
#pragma unroll
  for (int j = 0; j < 4; ++j) pk[j] = (u32)o[2*j] | ((u32)o[2*j+1] << 16);
  *(u32x4*)(xf + i) = pk;
}

// ---------------- qkv = x @ qkv_w^T + b (fp16 MFMA) ; relu/pos ; head-split ----------------
// 128x128 tile, BK=32, 4 waves, 2x16KB LDS -> 4 blocks/CU. LDS rows 64B (32 fp16),
// granule c (16B, 0..3) stored at slot c^(row&3): uniform 8 dwords/bank per b128 read.
__global__ __launch_bounds__(256, 4) void qkv_gemm_f16(
    const u16* __restrict__ xf, const u16* __restrict__ wf,
    const float* __restrict__ bias, const float* __restrict__ pos,
    u16* __restrict__ qo, u16* __restrict__ ko, u16* __restrict__ vo)
{
  __shared__ __align__(16) char lds[2][16384];   // A 8K | B 8K
  const int tid  = threadIdx.x;
  const int lane = tid & 63, wv = tid >> 6;
  const int L  = ((int)blockIdx.x & 7) * 1764 + ((int)blockIdx.x >> 3); // 14112 = 8*1764
  const int rt = L / 9, ct = L - rt * 9;
  const int m0 = rt * 128, t0 = ct * 128;

  const u16* spA[2];
  const u16* spB[2];
#pragma unroll
  for (int j = 0; j < 2; ++j) {
    int g = j * 256 + tid;
    int row = g >> 2, slot = g & 3;
    int c = slot ^ (row & 3);
    spA[j] = xf + (size_t)(m0 + row) * NC + c * 8;
    spB[j] = wf + (size_t)(t0 + row) * NC + c * 8;
  }

  auto stage = [&](char* buf) {
#pragma unroll
    for (int j = 0; j < 2; ++j) {
      gload_lds16(spA[j], buf + (j * 256 + tid) * 16);
      spA[j] += 32;
      gload_lds16(spB[j], buf + 8192 + (j * 256 + tid) * 16);
      spB[j] += 32;
    }
  };

  const int wm = (wv & 1) * 64, wn = (wv >> 1) * 64;
  const int l15 = lane & 15, l4 = lane >> 4;
  const int sl = l4 ^ (l15 & 3);
  int aoff[4], boff[4];
#pragma unroll
  for (int i = 0; i < 4; ++i) {
    aoff[i] = (wm + i * 16 + l15) * 64 + sl * 16;
    boff[i] = 8192 + (wn + i * 16 + l15) * 64 + sl * 16;
  }

  f4 acc[4][4];
  const f4 fz = {0.f, 0.f, 0.f, 0.f};
#pragma unroll
  for (int i = 0; i < 4; ++i)
#pragma unroll
    for (int j = 0; j < 4; ++j) acc[i][j] = fz;

  stage(lds[0]);
  for (int kt = 0; kt < 12; ++kt) {
    __syncthreads();
    if (kt < 11) stage(lds[(kt + 1) & 1]);
    char* buf = lds[kt & 1];
    hx8 af[4], bf4[4];
#pragma unroll
    for (int i = 0; i < 4; ++i) {
      af[i]  = *(const hx8*)(buf + aoff[i]);
      bf4[i] = *(const hx8*)(buf + boff[i]);
    }
#pragma unroll
    for (int mi = 0; mi < 4; ++mi)
#pragma unroll
      for (int ni = 0; ni < 4; ++ni)
        acc[mi][ni] = __builtin_amdgcn_mfma_f32_16x16x32_f16(af[mi], bf4[ni], acc[mi][ni], 0, 0, 0);
  }

  // epilogue: bias; q: relu->fp16 ; k: +pos,relu->fp16 ; v: ->bf16 ; head-split scatter
  const int s = ct / 3, cb = (ct - s * 3) * 128;   // s: 0=q 1=k 2=v
  float biasv[4];
#pragma unroll
  for (int ni = 0; ni < 4; ++ni) biasv[ni] = bias[t0 + wn + ni * 16 + l15];
#pragma unroll
  for (int mi = 0; mi < 4; ++mi) {
#pragma unroll
    for (int rr = 0; rr < 4; ++rr) {
      int m = m0 + wm + mi * 16 + l4 * 4 + rr;
      int b = m / 196, n = m - b * 196;
      size_t rowb = (size_t)b * 75264 + (size_t)n * 32;
#pragma unroll
      for (int ni = 0; ni < 4; ++ni) {
        int c = cb + wn + ni * 16 + l15;
        float val = acc[mi][ni][rr] + biasv[ni];
        size_t idx = rowb + (size_t)(c >> 5) * 6272 + (c & 31);
        if (s == 0)      { qo[idx] = f2h(fmaxf(val, 0.f)); }
        else if (s == 1) { ko[idx] = f2h(fmaxf(val + pos[n * 384 + c], 0.f)); }
        else             { vo[idx] = (u16)cvt_pk_bf16(val, val); }
      }
    }
  }
}

// ---------------- per-(b,h) linear attention + depthwise conv ----------------
// q,k fp16 ; v bf16 ; y fp16 (overlays k: k fully consumed in phase 2 before barrier).
// Phase 4: unpack-and-use q (NO qv[] array -> no scratch spill; round-6 lesson).
__global__ __launch_bounds__(256, 4) void attn_conv(
    const u16* __restrict__ q, const u16* k,
    const u16* __restrict__ v16, u16* y,
    const float* __restrict__ dwc_w, const float* __restrict__ dwc_b)
{
  __shared__ __align__(16) u16  sv[NN * 40];    // bf16 v, rows padded to 40 (80B)
  __shared__ __align__(16) u16  sfm[NN * 40];   // bf16 conv output
  __shared__ __align__(16) float skv[32 * 36];  // kv fp32, row pad 36
  __shared__ float sksum[32];

  const int tid = threadIdx.x;
  const size_t base = (size_t)blockIdx.x * PH;
  const u16* vp = v16 + base;
  const u16* kp = k + base;
  const u16* qp = q + base;
  u16* yp = y + base;
  char* svb  = (char*)sv;
  char* sfmb = (char*)sfm;

  // ---- phase 1: stage v bf16 -> padded LDS ----
  for (int c = tid; c < 784; c += 256) {
    u32x4 pk = *(const u32x4*)(vp + c * 8);
    *(u32x4*)(svb + (c >> 2) * 80 + (c & 3) * 16) = pk;
  }
  __syncthreads();

  // ---- phase 2: kv[c][d] = sum_n k[n][c]*v[n][d]  (8-way n-split + butterfly) ----
  {
    const int c = tid >> 3, ns = tid & 7;
    float acc[33];
#pragma unroll
    for (int d = 0; d < 33; ++d) acc[d] = 0.f;
    for (int i = 0; i < 25; ++i) {
      int n = i * 8 + ns;
      if (n < 196) {
        float kc = h2f(kp[n * 32 + c]);
#pragma unroll
        for (int g = 0; g < 4; ++g) {
          u32x4 r = *(const u32x4*)(svb + n * 80 + g * 16);
#pragma unroll
          for (int j = 0; j < 4; ++j) {
            acc[g * 8 + 2 * j]     += kc * bflo(r[j]);
            acc[g * 8 + 2 * j + 1] += kc * bfhi(r[j]);
          }
        }
        acc[32] += kc;
      }
    }
#pragma unroll
    for (int off = 1; off <= 4; off <<= 1) {
#pragma unroll
      for (int d = 0; d < 33; ++d) acc[d] += __shfl_xor(acc[d], off);
    }
    if (ns == 0) {
#pragma unroll
      for (int d4 = 0; d4 < 32; d4 += 4) {
        f4 w; w[0] = acc[d4]; w[1] = acc[d4+1]; w[2] = acc[d4+2]; w[3] = acc[d4+3];
        *(f4*)&skv[c * 36 + d4] = w;
      }
      sksum[c] = acc[32];
    }
  }

  // ---- phase 3: depthwise 5x5 conv on v (d-pair threads), fm -> bf16 LDS ----
  {
    const int dp = tid & 15, py = tid >> 4;
    if (py < 14) {
      const int d0 = 2 * dp;
      float fm0[14], fm1[14];
      const float b0 = dwc_b[d0], b1 = dwc_b[d0 + 1];
#pragma unroll
      for (int px = 0; px < 14; ++px) { fm0[px] = b0; fm1[px] = b1; }
#pragma unroll
      for (int ky = 0; ky < 5; ++ky) {
        int yy = py + ky - 2;
        if (yy < 0 || yy >= 14) continue;
        float w0[5], w1[5];
#pragma unroll
        for (int t = 0; t < 5; ++t) {
          w0[t] = dwc_w[d0 * 25 + ky * 5 + t];
          w1[t] = dwc_w[(d0 + 1) * 25 + ky * 5 + t];
        }
        float r0[14], r1[14];
#pragma unroll
        for (int xx = 0; xx < 14; ++xx) {
          u32 pr = *(const u32*)(svb + (yy * 14 + xx) * 80 + dp * 4);
          r0[xx] = bflo(pr); r1[xx] = bfhi(pr);
        }
#pragma unroll
        for (int px = 0; px < 14; ++px) {
#pragma unroll
          for (int kx = 0; kx < 5; ++kx) {
            int xx = px + kx - 2;
            if (xx < 0 || xx > 13) continue;
            fm0[px] += w0[kx] * r0[xx];
            fm1[px] += w1[kx] * r1[xx];
          }
        }
      }
#pragma unroll
      for (int px = 0; px < 14; ++px)
        *(u32*)(sfmb + (py * 14 + px) * 80 + dp * 4) = cvt_pk_bf16(fm0[px], fm1[px]);
    }
  }
  __syncthreads();

  // ---- phase 4: y = z*(q@kv) + fm ; write fp16 y ----
  {
    const int dp = tid & 15, ng = tid >> 4;
    const int d0 = 2 * dp;
    float kv0[32], kv1[32], ks[32];
#pragma unroll
    for (int c = 0; c < 32; ++c) {
      const float* p = &skv[c * 36 + d0];
      kv0[c] = p[0]; kv1[c] = p[1];
    }
#pragma unroll
    for (int c = 0; c < 32; ++c) ks[c] = sksum[c];
#pragma unroll 2
    for (int i = 0; i < 13; ++i) {
      int n = i * 16 + ng;
      if (n < 196) {
        float o0 = 0.f, o1 = 0.f, pz = 0.f;
#pragma unroll
        for (int g = 0; g < 4; ++g) {
          u32x4 qw = *(const u32x4*)(qp + (size_t)n * 32 + g * 8);
#pragma unroll
          for (int j = 0; j < 4; ++j) {
            float q0 = h2f((u16)(qw[j] & 0xffffu));
            float q1 = h2f((u16)(qw[j] >> 16));
            int c = g * 8 + 2 * j;
            o0 += q0 * kv0[c] + q1 * kv0[c + 1];
            o1 += q0 * kv1[c] + q1 * kv1[c + 1];
            pz += q0 * ks[c]  + q1 * ks[c + 1];
          }
        }
        float z = 1.f / (pz + 1e-6f);
        u32 fmp = *(const u32*)(sfmb + n * 80 + dp * 4);
        float r0 = fmaf(o0, z, bflo(fmp));
        float r1 = fmaf(o1, z, bfhi(fmp));
        *(u32*)(yp + n * 32 + d0) = (u32)f2h(r0) | ((u32)f2h(r1) << 16);
      }
    }
  }
}

// ---------------- out = y @ proj_w^T + proj_b (fp16 MFMA) ----------------
__global__ __launch_bounds__(256, 4) void proj_gemm_f16(
    const u16* __restrict__ yf, const u16* __restrict__ wf,
    const float* __restrict__ bias, float* __restrict__ out)
{
  __shared__ __align__(16) char lds[2][16384];   // A 8K | B 8K
  const int tid  = threadIdx.x;
  const int lane = tid & 63, wv = tid >> 6;
  const int L  = ((int)blockIdx.x & 7) * 588 + ((int)blockIdx.x >> 3);  // 4704 = 8*588
  const int rt = L / 3, ct = L - rt * 3;
  const int m0 = rt * 128, t0 = ct * 128;

  const u16* spA[2];
  const u16* spB[2];
#pragma unroll
  for (int j = 0; j < 2; ++j) {
    int g = j * 256 + tid;
    int row = g >> 2, slot = g & 3;
    int c = slot ^ (row & 3);
    int m = m0 + row;
    int b = m / 196, n = m - b * 196;
    spA[j] = yf + (size_t)b * 75264 + n * 32 + c * 8;   // += 6272 per head (K-step)
    spB[j] = wf + (size_t)(t0 + row) * NC + c * 8;
  }

  auto stage = [&](char* buf) {
#pragma unroll
    for (int j = 0; j < 2; ++j) {
      gload_lds16(spA[j], buf + (j * 256 + tid) * 16);
      spA[j] += 6272;
      gload_lds16(spB[j], buf + 8192 + (j * 256 + tid) * 16);
      spB[j] += 32;
    }
  };

  const int wm = (wv & 1) * 64, wn = (wv >> 1) * 64;
  const int l15 = lane & 15, l4 = lane >> 4;
  const int sl = l4 ^ (l15 & 3);
  int aoff[4], boff[4];
#pragma unroll
  for (int i = 0; i < 4; ++i) {
    aoff[i] = (wm + i * 16 + l15) * 64 + sl * 16;
    boff[i] = 8192 + (wn + i * 16 + l15) * 64 + sl * 16;
  }

  f4 acc[4][4];
  const f4 fz = {0.f, 0.f, 0.f, 0.f};
#pragma unroll
  for (int i = 0; i < 4; ++i)
#pragma unroll
    for (int j = 0; j < 4; ++j) acc[i][j] = fz;

  stage(lds[0]);
  for (int kt = 0; kt < 12; ++kt) {
    __syncthreads();
    if (kt < 11) stage(lds[(kt + 1) & 1]);
    char* buf = lds[kt & 1];
    hx8 af[4], bf4[4];
#pragma unroll
    for (int i = 0; i < 4; ++i) {
      af[i]  = *(const hx8*)(buf + aoff[i]);
      bf4[i] = *(const hx8*)(buf + boff[i]);
    }
#pragma unroll
    for (int mi = 0; mi < 4; ++mi)
#pragma unroll
      for (int ni = 0; ni < 4; ++ni)
        acc[mi][ni] = __builtin_amdgcn_mfma_f32_16x16x32_f16(af[mi], bf4[ni], acc[mi][ni], 0, 0, 0);
  }

  float biasv[4];
#pragma unroll
  for (int ni = 0; ni < 4; ++ni) biasv[ni] = bias[t0 + wn + ni * 16 + l15];
#pragma unroll
  for (int mi = 0; mi < 4; ++mi) {
#pragma unroll
    for (int rr = 0; rr < 4; ++rr) {
      int m = m0 + wm + mi * 16 + l4 * 4 + rr;
      size_t ob = (size_t)m * 384 + t0 + wn;
#pragma unroll
      for (int ni = 0; ni < 4; ++ni)
        out[ob + ni * 16 + l15] = acc[mi][ni][rr] + biasv[ni];
    }
  }
}

// ---------------- launcher ----------------
extern "C" void kernel_launch(void* const* d_in, const int* in_sizes, int n_in,
                              void* d_out, int out_size, void* d_ws, size_t ws_size,
                              hipStream_t stream)
{
  const float* x      = (const float*)d_in[0];
  const float* qkv_w  = (const float*)d_in[1];
  const float* qkv_b  = (const float*)d_in[2];
  const float* proj_w = (const float*)d_in[3];
  const float* proj_b = (const float*)d_in[4];
  const float* dwc_w  = (const float*)d_in[5];
  const float* dwc_b  = (const float*)d_in[6];
  const float* pos    = (const float*)d_in[7];
  float* out = (float*)d_out;
  char* ws = (char*)d_ws;

  u16* qb  = (u16*)(ws + OFF_Q);     // q fp16
  u16* kb  = (u16*)(ws + OFF_K);     // k fp16
  u16* vb  = (u16*)(ws + OFF_V);     // v bf16
  u16* wqf = (u16*)(ws + OFF_WQF);
  u16* wpf = (u16*)(ws + OFF_WPF);
  u16* xf  = (u16*)(ws + OFF_XF);
  u16* yb  = (u16*)(ws + OFF_K);     // y fp16 overlays k (consumed in attn phase 2)

  split_weights<<<1728, 256, 0, stream>>>(qkv_w, proj_w, wqf, wpf);
  cvt_x_f16<<<37632, 256, 0, stream>>>(x, xf);
  qkv_gemm_f16<<<14112, 256, 0, stream>>>(xf, wqf, qkv_b, pos, qb, kb, vb);
  attn_conv<<<12288, 256, 0, stream>>>(qb, kb, vb, yb, dwc_w, dwc_b);
  proj_gemm_f16<<<4704, 256, 0, stream>>>(yb, wpf, proj_b, out);
}